// Round 1
// baseline (202.976 us; speedup 1.0000x reference)
//
#include <hip/hip_runtime.h>

#define NROWS 32768
#define DIM   128
#define KCODES 4096
#define DECAYF 0.8f
#define EPSF 1e-5f
#define COMMITW 0.25f

typedef _Float16 half8 __attribute__((ext_vector_type(8)));
typedef _Float16 half2v __attribute__((ext_vector_type(2)));
typedef float float4v __attribute__((ext_vector_type(4)));

// ---------------- embed -> staged split planes + e2 ----------------
// estg layout (halves): [chunk][slice][code6][8], slice = pl*16 + ks*4 + q.
// Exactly MFMA B-fragment order -> direct coalesced register loads.
__global__ __launch_bounds__(256) void esplit_kernel(const float* __restrict__ embed,
                                                     _Float16* __restrict__ estg,
                                                     float* __restrict__ e2h) {
    int code = blockIdx.x * 4 + (threadIdx.x >> 6);
    int lane = threadIdx.x & 63;
    float2 v = ((const float2*)(embed + (size_t)code * DIM))[lane];
    float s = v.x * v.x + v.y * v.y;
    #pragma unroll
    for (int off = 32; off > 0; off >>= 1) s += __shfl_down(s, off, 64);
    if (lane == 0) e2h[code] = 0.5f * s;

    int d = lane * 2;
    int ks = d >> 5, q = (d >> 3) & 3, j = d & 7;
    _Float16 h0 = (_Float16)v.x, l0 = (_Float16)(v.x - (float)h0);
    _Float16 h1 = (_Float16)v.y, l1 = (_Float16)(v.y - (float)h1);
    int chunk = code >> 6, c6 = code & 63;
    size_t base = (size_t)chunk * 16384;
    size_t hidx = base + (size_t)(( 0 + ks * 4 + q) * 64 + c6) * 8 + j;
    size_t lidx = base + (size_t)((16 + ks * 4 + q) * 64 + c6) * 8 + j;
    *(half2v*)&estg[hidx] = (half2v){h0, h1};
    *(half2v*)&estg[lidx] = (half2v){l0, l1};
}

// ---------------- MFMA argmax: 128 rows/block, 16 waves, barrier-free ------
// R1 change: occupancy. Old: 64-row A-tiles -> 256 regs/wave -> 2 waves/SIMD,
// MfmaUtil 45%. New: 32-row A-tiles (Ah/Al = 64 VGPRs), 1024 thr / 16 waves
// (j = w&3 code-tile, rh = w>>2 row-quarter), per-ks B ping-pong (2 slots x
// 8 regs) instead of whole-chunk dbuf. Target <=128 regs -> 4 waves/SIMD.
// 4 rh-waves share each j's B-frags in the same chunk window -> L1 reuse;
// estg (2 MB) stays L2-resident. Still no barriers in the K-loop.
__global__ __launch_bounds__(1024, 4) void argmax_kernel(const float* __restrict__ x,
                                                         const _Float16* __restrict__ estg,
                                                         const float* __restrict__ e2h,
                                                         int* __restrict__ ind,
                                                         float* __restrict__ out_ind,
                                                         int* __restrict__ bins,
                                                         float* __restrict__ loss) {
    __shared__ float rv[16][32];
    __shared__ int   ri[16][32];
    __shared__ float x2s[128];

    int tid = threadIdx.x;
    int lane = tid & 63;
    int w = tid >> 6;          // 0..15
    int j = w & 3;             // code-tile
    int rh = w >> 2;           // row-quarter 0..3
    int m15 = lane & 15;
    int q = (lane >> 4) & 3;
    int n0 = blockIdx.x * 128;

    // A frags for this wave's 32 rows (rows n0 + rh*32 + rt*16 + m15)
    half8 Ah[2][4], Al[2][4];
    float xsq[2];
    #pragma unroll
    for (int rt = 0; rt < 2; ++rt) {
        xsq[rt] = 0.f;
        #pragma unroll
        for (int ks = 0; ks < 4; ++ks) {
            const float* p = x + (size_t)(n0 + rh * 32 + rt * 16 + m15) * DIM + ks * 32 + q * 8;
            float4 a = *(const float4*)p;
            float4 b = *(const float4*)(p + 4);
            float f[8] = {a.x, a.y, a.z, a.w, b.x, b.y, b.z, b.w};
            half8 H, L;
            #pragma unroll
            for (int e = 0; e < 8; ++e) {
                _Float16 h = (_Float16)f[e];
                H[e] = h;
                L[e] = (_Float16)(f[e] - (float)h);
                xsq[rt] += f[e] * f[e];
            }
            Ah[rt][ks] = H;
            Al[rt][ks] = L;
        }
        xsq[rt] += __shfl_xor(xsq[rt], 16, 64);
        xsq[rt] += __shfl_xor(xsq[rt], 32, 64);
    }
    if (j == 0 && lane < 16) {
        #pragma unroll
        for (int rt = 0; rt < 2; ++rt) x2s[rh * 32 + rt * 16 + m15] = xsq[rt];
    }

    float best[2][4];
    int   bidx[2][4];
    #pragma unroll
    for (int rt = 0; rt < 2; ++rt)
        #pragma unroll
        for (int r = 0; r < 4; ++r) { best[rt][r] = -3.0e38f; bidx[rt][r] = 0; }

    const int cm = j * 16 + m15;
    const _Float16* cb = estg + (size_t)cm * 8 + (size_t)q * 512;

    half8 BhA, BlA, BhB, BlB;
    float e2cur, e2nxt;

    // prefetch (ch=0, ks=0) -> slot A
    BhA = *(const half8*)(cb);
    BlA = *(const half8*)(cb + 8192);
    e2cur = e2h[cm];

    #pragma unroll 1
    for (int ch = 0; ch < 64; ++ch) {
        float4v acc[2];
        #pragma unroll
        for (int rt = 0; rt < 2; ++rt) acc[rt] = (float4v){-e2cur, -e2cur, -e2cur, -e2cur};

        // step 0: issue ks1 -> B, compute ks0 from A
        BhB = *(const half8*)(cb + 2048);
        BlB = *(const half8*)(cb + 8192 + 2048);
        #pragma unroll
        for (int rt = 0; rt < 2; ++rt) {
            acc[rt] = __builtin_amdgcn_mfma_f32_16x16x32_f16(Ah[rt][0], BhA, acc[rt], 0, 0, 0);
            acc[rt] = __builtin_amdgcn_mfma_f32_16x16x32_f16(Al[rt][0], BhA, acc[rt], 0, 0, 0);
            acc[rt] = __builtin_amdgcn_mfma_f32_16x16x32_f16(Ah[rt][0], BlA, acc[rt], 0, 0, 0);
        }
        // step 1: issue ks2 -> A, compute ks1 from B
        BhA = *(const half8*)(cb + 4096);
        BlA = *(const half8*)(cb + 8192 + 4096);
        #pragma unroll
        for (int rt = 0; rt < 2; ++rt) {
            acc[rt] = __builtin_amdgcn_mfma_f32_16x16x32_f16(Ah[rt][1], BhB, acc[rt], 0, 0, 0);
            acc[rt] = __builtin_amdgcn_mfma_f32_16x16x32_f16(Al[rt][1], BhB, acc[rt], 0, 0, 0);
            acc[rt] = __builtin_amdgcn_mfma_f32_16x16x32_f16(Ah[rt][1], BlB, acc[rt], 0, 0, 0);
        }
        // step 2: issue ks3 -> B, compute ks2 from A
        BhB = *(const half8*)(cb + 6144);
        BlB = *(const half8*)(cb + 8192 + 6144);
        #pragma unroll
        for (int rt = 0; rt < 2; ++rt) {
            acc[rt] = __builtin_amdgcn_mfma_f32_16x16x32_f16(Ah[rt][2], BhA, acc[rt], 0, 0, 0);
            acc[rt] = __builtin_amdgcn_mfma_f32_16x16x32_f16(Al[rt][2], BhA, acc[rt], 0, 0, 0);
            acc[rt] = __builtin_amdgcn_mfma_f32_16x16x32_f16(Ah[rt][2], BlA, acc[rt], 0, 0, 0);
        }
        // step 3: issue (ch+1, ks0) -> A (+ e2 of ch+1), compute ks3 from B
        // (ch=63 prefetch runs past estg into the adjacent workspace region:
        //  allocated, values never consumed)
        BhA = *(const half8*)(cb + 16384);
        BlA = *(const half8*)(cb + 16384 + 8192);
        e2nxt = e2h[(ch + 1) * 64 + cm];
        #pragma unroll
        for (int rt = 0; rt < 2; ++rt) {
            acc[rt] = __builtin_amdgcn_mfma_f32_16x16x32_f16(Ah[rt][3], BhB, acc[rt], 0, 0, 0);
            acc[rt] = __builtin_amdgcn_mfma_f32_16x16x32_f16(Al[rt][3], BhB, acc[rt], 0, 0, 0);
            acc[rt] = __builtin_amdgcn_mfma_f32_16x16x32_f16(Ah[rt][3], BlB, acc[rt], 0, 0, 0);
        }

        int c = ch * 64 + cm;
        #pragma unroll
        for (int rt = 0; rt < 2; ++rt)
            #pragma unroll
            for (int r = 0; r < 4; ++r) {
                float s = acc[rt][r];
                if (s > best[rt][r]) { best[rt][r] = s; bidx[rt][r] = c; }
            }
        e2cur = e2nxt;
        cb += 16384;
    }

    // reduce across the 16 code-lanes (m15); min index on ties
    #pragma unroll
    for (int rt = 0; rt < 2; ++rt)
        #pragma unroll
        for (int r = 0; r < 4; ++r) {
            float bv = best[rt][r];
            int   bi = bidx[rt][r];
            #pragma unroll
            for (int m = 1; m <= 8; m <<= 1) {
                float ov = __shfl_xor(bv, m, 64);
                int   oi = __shfl_xor(bi, m, 64);
                if (ov > bv || (ov == bv && oi < bi)) { bv = ov; bi = oi; }
            }
            if (m15 == 0) {
                int rl = rt * 16 + q * 4 + r;
                rv[w][rl] = bv;
                ri[w][rl] = bi;
            }
        }
    __syncthreads();
    if (tid < 128) {
        int rh2 = tid >> 5;      // row-quarter
        int rl  = tid & 31;      // row within quarter
        float bv = rv[rh2 * 4][rl];
        int   bi = ri[rh2 * 4][rl];
        #pragma unroll
        for (int jj = 1; jj < 4; ++jj) {
            float ov = rv[rh2 * 4 + jj][rl];
            int   oi = ri[rh2 * 4 + jj][rl];
            if (ov > bv || (ov == bv && oi < bi)) { bv = ov; bi = oi; }
        }
        ind[n0 + tid] = bi;
        out_ind[n0 + tid] = (float)bi;
        atomicAdd(&bins[bi], 1);
        // commit-loss partial: |x - e_k|^2 = |x|^2 - 2*best_score
        float lp = x2s[tid] - 2.0f * bv;
        #pragma unroll
        for (int off = 32; off > 0; off >>= 1) lp += __shfl_down(lp, off, 64);
        if ((tid & 63) == 0) atomicAdd(loss, lp);
    }
}

// ---------------- scan: shuffle-based, 2 barriers ----------------
__global__ __launch_bounds__(1024) void scan_kernel(const int* __restrict__ bins,
                                                    const float* __restrict__ cluster_size,
                                                    const float* __restrict__ loss,
                                                    int* __restrict__ offsets,
                                                    int* __restrict__ cursor,
                                                    float* __restrict__ out_cs,
                                                    float* __restrict__ ntot,
                                                    float* __restrict__ out_loss) {
    __shared__ int   wtot[16];
    __shared__ float fred[16];
    int t = threadIdx.x;
    int lane = t & 63, wv = t >> 6;
    int b[4];
    float cs[4];
    float csum = 0.f;
    int s = 0;
    #pragma unroll
    for (int e = 0; e < 4; ++e) {
        b[e] = bins[t * 4 + e];
        s += b[e];
        cs[e] = cluster_size[t * 4 + e] * DECAYF + (1.0f - DECAYF) * (float)b[e];
        csum += cs[e];
    }
    int sc = s;
    #pragma unroll
    for (int off = 1; off < 64; off <<= 1) {
        int v = __shfl_up(sc, off, 64);
        if (lane >= off) sc += v;
    }
    float fc = csum;
    #pragma unroll
    for (int off = 32; off > 0; off >>= 1) fc += __shfl_down(fc, off, 64);
    if (lane == 63) wtot[wv] = sc;
    if (lane == 0) fred[wv] = fc;
    __syncthreads();
    if (t < 16) {
        int v = wtot[t];
        int scv = v;
        #pragma unroll
        for (int off = 1; off < 16; off <<= 1) {
            int u = __shfl_up(scv, off, 64);
            if (t >= off) scv += u;
        }
        wtot[t] = scv - v;
    }
    if (t == 0) {
        float tot = 0.f;
        #pragma unroll
        for (int i = 0; i < 16; ++i) tot += fred[i];
        *ntot = tot;
        *out_loss = COMMITW * (*loss) / (float)((size_t)NROWS * DIM);
    }
    __syncthreads();
    int ex = sc - s + wtot[wv];
    #pragma unroll
    for (int e = 0; e < 4; ++e) {
        offsets[t * 4 + e] = ex;
        cursor[t * 4 + e] = ex;
        out_cs[t * 4 + e] = cs[e];
        ex += b[e];
    }
}

// ---------------- reorder rows by code (also emit sorted code list) --------
__global__ __launch_bounds__(256) void reorder_kernel(const int* __restrict__ ind,
                                                      int* __restrict__ cursor,
                                                      int* __restrict__ rowids,
                                                      int* __restrict__ codesorted) {
    int row = blockIdx.x * 256 + threadIdx.x;
    int k = ind[row];
    int pos = atomicAdd(&cursor[k], 1);
    rowids[pos] = row;
    codesorted[pos] = k;
}

// ---------------- segmented esum + out_q: fixed 16-row windows -------------
#define WROWS 16
__global__ __launch_bounds__(256) void segred_kernel(const float* __restrict__ x,
                                                     const float* __restrict__ embed,
                                                     const int* __restrict__ rowids,
                                                     const int* __restrict__ codesorted,
                                                     const int* __restrict__ offsets,
                                                     const int* __restrict__ bins,
                                                     float* __restrict__ esum,
                                                     float* __restrict__ out_q) {
    int tid = threadIdx.x;
    int lane = tid & 63;
    int wv = blockIdx.x * 4 + (tid >> 6);
    int w0 = wv * WROWS;

    int i16 = lane & (WROWS - 1);
    int rowv = rowids[w0 + i16];
    int kv   = codesorted[w0 + i16];

    float2 xv[WROWS];
    #pragma unroll
    for (int i = 0; i < WROWS; ++i) {
        int row = __shfl(rowv, i, 64);
        xv[i] = ((const float2*)(x + (size_t)row * DIM))[lane];
    }

    int curk = __shfl(kv, 0, 64);
    float2 qv = ((const float2*)(embed + (size_t)curk * DIM))[lane];
    float2 acc = {0.f, 0.f};

    #pragma unroll
    for (int i = 0; i < WROWS; ++i) {
        int row = __shfl(rowv, i, 64);
        int k   = __shfl(kv, i, 64);
        if (k != curk) {
            int sbeg = offsets[curk];
            int send = sbeg + bins[curk];
            float* ep = esum + (size_t)curk * DIM + lane * 2;
            if (sbeg >= w0 && send <= w0 + WROWS) {
                *(float2*)ep = acc;
            } else {
                atomicAdd(ep, acc.x);
                atomicAdd(ep + 1, acc.y);
            }
            curk = k;
            acc = (float2){0.f, 0.f};
            qv = ((const float2*)(embed + (size_t)curk * DIM))[lane];
        }
        acc.x += xv[i].x;
        acc.y += xv[i].y;
        ((float2*)(out_q + (size_t)row * DIM))[lane] = qv;
    }
    {
        int sbeg = offsets[curk];
        int send = sbeg + bins[curk];
        float* ep = esum + (size_t)curk * DIM + lane * 2;
        if (sbeg >= w0 && send <= w0 + WROWS) {
            *(float2*)ep = acc;
        } else {
            atomicAdd(ep, acc.x);
            atomicAdd(ep + 1, acc.y);
        }
    }
}

// ---------------- norm: out_norm from esum (streaming) ----------------
__global__ __launch_bounds__(256) void norm_kernel(const float* __restrict__ esum,
                                                   const float* __restrict__ embed_avg,
                                                   const float* __restrict__ out_cs,
                                                   const float* __restrict__ ntot,
                                                   float* __restrict__ out_norm) {
    int idx = blockIdx.x * 256 + threadIdx.x;
    int k = idx >> 6;
    float nt = *ntot;
    float cs = out_cs[k];
    float cluster = (cs + EPSF) / (nt + (float)KCODES * EPSF) * nt;
    float inv = 1.0f / cluster;
    float2 es = ((const float2*)esum)[idx];
    float2 ea = ((const float2*)embed_avg)[idx];
    float2 o;
    o.x = (ea.x * DECAYF + (1.0f - DECAYF) * es.x) * inv;
    o.y = (ea.y * DECAYF + (1.0f - DECAYF) * es.y) * inv;
    ((float2*)out_norm)[idx] = o;
}

extern "C" void kernel_launch(void* const* d_in, const int* in_sizes, int n_in,
                              void* d_out, int out_size, void* d_ws, size_t ws_size,
                              hipStream_t stream) {
    const float* x            = (const float*)d_in[0];
    const float* embed        = (const float*)d_in[1];
    const float* cluster_size = (const float*)d_in[2];
    const float* embed_avg    = (const float*)d_in[3];

    float* out      = (float*)d_out;
    float* out_q    = out;                               // 4194304
    float* out_ind  = out + 4194304;                     // 32768
    float* out_loss = out_ind + 32768;                   // 1
    float* out_cs   = out_loss + 1;                      // 4096
    float* out_norm = out_cs + 4096;                     // 524288

    // workspace layout (bytes)
    char* ws = (char*)d_ws;
    _Float16* estg = (_Float16*)ws;                      // 2,097,152
    float* e2h   = (float*)(ws + 2097152);               // 16,384
    int*   ind   = (int*)(ws + 2113536);                 // 131,072
    int*   offsets = (int*)(ws + 2244608);               // 16,384
    int*   cursor  = (int*)(ws + 2260992);               // 16,384
    int*   rowids  = (int*)(ws + 2277376);               // 131,072
    int*   codesorted = (int*)(ws + 2408448);            // 131,072
    float* loss  = (float*)(ws + 2539520);               // 4 (pad to 256)
    float* ntot  = loss + 1;
    int*   bins  = (int*)(ws + 2539776);                 // 16,384
    float* esum  = (float*)(ws + 2556160);               // 2,097,152

    // zero loss/pad + bins + esum (contiguous)
    hipMemsetAsync(ws + 2539520, 0, 256 + 16384 + 2097152, stream);

    esplit_kernel<<<KCODES / 4, 256, 0, stream>>>(embed, estg, e2h);
    argmax_kernel<<<NROWS / 128, 1024, 0, stream>>>(x, estg, e2h, ind, out_ind,
                                                    bins, loss);
    scan_kernel<<<1, 1024, 0, stream>>>(bins, cluster_size, loss, offsets, cursor,
                                        out_cs, ntot, out_loss);
    reorder_kernel<<<NROWS / 256, 256, 0, stream>>>(ind, cursor, rowids, codesorted);
    segred_kernel<<<NROWS / WROWS / 4, 256, 0, stream>>>(x, embed, rowids, codesorted,
                                                         offsets, bins, esum, out_q);
    norm_kernel<<<KCODES * DIM / 2 / 256, 256, 0, stream>>>(esum, embed_avg, out_cs,
                                                            ntot, out_norm);
}